// Round 5
// baseline (320.889 us; speedup 1.0000x reference)
//
#include <hip/hip_runtime.h>
#include <math.h>

#define EMBED 1024
#define NHEAD 16
#define HDIM  64
#define BATCH 4
#define SEQ   2048
#define MROWS (BATCH * SEQ)   // 8192

typedef __attribute__((ext_vector_type(8))) short short8;
typedef __attribute__((ext_vector_type(4))) float floatx4;
typedef __attribute__((ext_vector_type(16))) float floatx16;

#if __has_builtin(__builtin_amdgcn_exp2f)
#define EXP2(x) __builtin_amdgcn_exp2f(x)
#else
#define EXP2(x) exp2f(x)
#endif

// RNE float -> bf16 (finite inputs only).
__device__ __forceinline__ unsigned short f2bf(float f) {
  unsigned u = __float_as_uint(f);
  u += 0x7fffu + ((u >> 16) & 1u);
  return (unsigned short)(u >> 16);
}

// Pack two floats as a bf16 pair. gfx950 has v_cvt_pk_bf16_f32 (1 VALU op).
#if __has_builtin(__builtin_amdgcn_cvt_pk_bf16_f32)
__device__ __forceinline__ unsigned pack2bf(float lo, float hi) {
  typedef __attribute__((ext_vector_type(2))) __bf16 bf2;
  union { bf2 b; unsigned u; } c;
  c.b = __builtin_amdgcn_cvt_pk_bf16_f32(lo, hi);
  return c.u;
}
#else
__device__ __forceinline__ unsigned pack2bf(float lo, float hi) {
  return ((__float_as_uint(lo) + 0x8000u) >> 16) |
         ((__float_as_uint(hi) + 0x8000u) & 0xffff0000u);
}
#endif

// Async global->LDS, 16 B per lane. lds dest = uniform base + lane*16.
__device__ __forceinline__ void gl_lds16(const void* g, void* l) {
  __builtin_amdgcn_global_load_lds(
      (const __attribute__((address_space(1))) unsigned int*)g,
      (__attribute__((address_space(3))) unsigned int*)l, 16, 0, 0);
}

// ---------------------------------------------------------------------------
// Cast fp32 -> bf16: x (8M elems) + 4 weights (1M each, contiguous dst).
// ---------------------------------------------------------------------------
__global__ __launch_bounds__(256) void cast_bf16_kernel(
    const float* __restrict__ x,  const float* __restrict__ wq,
    const float* __restrict__ wk, const float* __restrict__ wv,
    const float* __restrict__ wo,
    unsigned short* __restrict__ xb, unsigned short* __restrict__ wb) {
  const size_t NX = (size_t)MROWS * EMBED;                 // 2^23
  size_t i4 = ((size_t)blockIdx.x * 256 + threadIdx.x) * 4;
  const float* src;
  unsigned short* dst;
  size_t off;
  if (i4 < NX) {
    src = x; dst = xb; off = i4;
  } else {
    size_t j = i4 - NX;
    int r = (int)(j >> 20);
    off = j & ((1u << 20) - 1);
    src = (r == 0) ? wq : (r == 1) ? wk : (r == 2) ? wv : wo;
    dst = wb + ((size_t)r << 20);
  }
  float4 v = *(const float4*)(src + off);
  ushort4 o;
  o.x = f2bf(v.x); o.y = f2bf(v.y); o.z = f2bf(v.z); o.w = f2bf(v.w);
  *(ushort4*)(dst + off) = o;
}

// ---------------------------------------------------------------------------
// Shared 128x128xK bf16 GEMM core (m97 structure): Y = A @ B^T fragments.
// ---------------------------------------------------------------------------
__device__ __forceinline__ void gemm_core(
    const unsigned short* __restrict__ Amat,
    const unsigned short* __restrict__ Bmat,
    int mBase, int nBase,
    unsigned short* As, unsigned short* Bs,
    floatx4 acc[4][4]) {
  const int t = threadIdx.x;
  const int lane = t & 63, w = t >> 6;
  const int wr = w >> 1, wc = w & 1;
  const int quad = lane >> 4, l15 = lane & 15;

  const int f0 = (w * 2 + 0) * 64 + lane;
  const int f1 = (w * 2 + 1) * 64 + lane;
  const unsigned short* ga0 = Amat + (size_t)(mBase + (f0 >> 2)) * EMBED + (f0 & 3) * 8;
  const unsigned short* ga1 = Amat + (size_t)(mBase + (f1 >> 2)) * EMBED + (f1 & 3) * 8;
  const unsigned short* gb0 = Bmat + (size_t)(nBase + (f0 >> 2)) * EMBED + (f0 & 3) * 8;
  const unsigned short* gb1 = Bmat + (size_t)(nBase + (f1 >> 2)) * EMBED + (f1 & 3) * 8;
  unsigned short* la0 = As + (w * 2 + 0) * 512;
  unsigned short* la1 = As + (w * 2 + 1) * 512;
  unsigned short* lb0 = Bs + (w * 2 + 0) * 512;
  unsigned short* lb1 = Bs + (w * 2 + 1) * 512;

  for (int kb = 0; kb < EMBED; kb += 32) {
    __syncthreads();
    gl_lds16(ga0 + kb, la0);
    gl_lds16(ga1 + kb, la1);
    gl_lds16(gb0 + kb, lb0);
    gl_lds16(gb1 + kb, lb1);
    __syncthreads();
    short8 a[4], b[4];
#pragma unroll
    for (int mi = 0; mi < 4; ++mi)
      a[mi] = *(const short8*)&As[(wr * 64 + mi * 16 + l15) * 32 + quad * 8];
#pragma unroll
    for (int ni = 0; ni < 4; ++ni)
      b[ni] = *(const short8*)&Bs[(wc * 64 + ni * 16 + l15) * 32 + quad * 8];
#pragma unroll
    for (int mi = 0; mi < 4; ++mi)
#pragma unroll
      for (int ni = 0; ni < 4; ++ni)
        acc[mi][ni] = __builtin_amdgcn_mfma_f32_16x16x32_bf16(
            a[mi], b[ni], acc[mi][ni], 0, 0, 0);
  }
}

// ---------------------------------------------------------------------------
// QKV projection. Q is pre-scaled by C=(1/8)*log2(e) so attention's exp2
// argument is the raw QK^T score. Q,K: bf16 [b,h,s,d]; V: [b,h,d,s].
// ---------------------------------------------------------------------------
__global__ __launch_bounds__(256) void proj_qkv_bf16(
    const unsigned short* __restrict__ xb,
    const unsigned short* __restrict__ wb,
    unsigned short* __restrict__ qkv) {
  const int which = blockIdx.z;
  const unsigned short* W = wb + ((size_t)which << 20);
  const int nBase = blockIdx.x * 128;
  const int mBase = blockIdx.y * 128;

  __shared__ unsigned short As[128 * 32];
  __shared__ unsigned short Bs[128 * 32];

  floatx4 acc[4][4] = {};
  gemm_core(xb, W, mBase, nBase, As, Bs, acc);

  const int t = threadIdx.x;
  const int lane = t & 63, w = t >> 6;
  const int wr = w >> 1, wc = w & 1;
  const int quad = lane >> 4, l15 = lane & 15;

  unsigned short* out = qkv + (size_t)which * MROWS * EMBED;
  if (which < 2) {
    const float scale = (which == 0) ? 0.18033688f : 1.0f;  // (1/8)*log2(e)
#pragma unroll
    for (int mi = 0; mi < 4; ++mi)
#pragma unroll
      for (int ni = 0; ni < 4; ++ni) {
        const int n = nBase + wc * 64 + ni * 16 + l15;
        const int h = n >> 6, d = n & 63;
#pragma unroll
        for (int r = 0; r < 4; ++r) {
          const int m = mBase + wr * 64 + mi * 16 + quad * 4 + r;
          const int b = m >> 11, s = m & (SEQ - 1);
          out[(((size_t)(b * NHEAD + h) * SEQ) + s) * HDIM + d] =
              f2bf(acc[mi][ni][r] * scale);
        }
      }
  } else {
    // V^T: [b,h,d,s] — 4 consecutive s per lane -> packed 8 B store.
#pragma unroll
    for (int mi = 0; mi < 4; ++mi) {
      const int m0 = mBase + wr * 64 + mi * 16 + quad * 4;
      const int b = m0 >> 11, s0 = m0 & (SEQ - 1);
#pragma unroll
      for (int ni = 0; ni < 4; ++ni) {
        const int n = nBase + wc * 64 + ni * 16 + l15;
        const int h = n >> 6, d = n & 63;
        ushort4 pk;
        pk.x = f2bf(acc[mi][ni][0]); pk.y = f2bf(acc[mi][ni][1]);
        pk.z = f2bf(acc[mi][ni][2]); pk.w = f2bf(acc[mi][ni][3]);
        *(ushort4*)&out[((size_t)(b * NHEAD + h) * HDIM + d) * SEQ + s0] = pk;
      }
    }
  }
}

// ---------------------------------------------------------------------------
// MFMA flash attention, 32x32x16, transposed-score, double-buffered staging.
//
// Grid: 1-D, XCD-swizzled so each bh's 16 query-blocks land on one XCD
// (K/V served from that XCD's L2 after one HBM fetch).
// K-loop: single barrier per 64-key tile; stage(t+1) issued after the
// barrier into the other LDS half, overlapping compute(t). The barrier's
// vmcnt(0) drain then only waits for loads issued one full compute ago.
// ---------------------------------------------------------------------------
__global__ __launch_bounds__(256) void attn_mfma(
    const unsigned short* __restrict__ qkv,
    unsigned short* __restrict__ aout) {
  const unsigned short* Q = qkv;
  const unsigned short* K = qkv + (size_t)MROWS * EMBED;
  const unsigned short* V = qkv + 2 * (size_t)MROWS * EMBED;

  // XCD-locality decode: id = slot*8 + xcd; bh = xcd*8 + slot/16.
  const int id = blockIdx.x;
  const int xcd = id & 7, slot = id >> 3;
  const int bh = xcd * 8 + (slot >> 4);
  const int qBase = (slot & 15) * 128;

  __shared__ unsigned short Ks[2 * 64 * 64];   // [buf][key][d], swizzled
  __shared__ unsigned short Vs[2 * 64 * 64];   // [buf][d][key], swizzled

  const int t = threadIdx.x;
  const int lane = t & 63, w = t >> 6;
  const int h2 = lane >> 5;     // lane half (k-group selector in A/B frags)
  const int q31 = lane & 31;    // query within wave / row within tile

  // Q B-frags (pre-scaled by (1/8)*log2e): B[k=d][n=q].
  const unsigned short* qrow =
      Q + ((size_t)bh * SEQ + qBase + w * 32 + q31) * HDIM;
  short8 qa[4];
#pragma unroll
  for (int ds = 0; ds < 4; ++ds)
    qa[ds] = *(const short8*)(qrow + ds * 16 + h2 * 8);

  // Staging source addresses (swizzled), hoisted.
  const int f0 = (w * 2 + 0) * 64 + lane;
  const int f1 = (w * 2 + 1) * 64 + lane;
  const int kr0 = f0 >> 3, kg0 = (f0 & 7) ^ (kr0 & 7);
  const int kr1 = f1 >> 3, kg1 = (f1 & 7) ^ (kr1 & 7);
  const unsigned short* kbase = K + (size_t)bh * SEQ * HDIM;
  const unsigned short* vbase = V + (size_t)bh * HDIM * SEQ;
  const unsigned short* gk0 = kbase + (size_t)kr0 * HDIM + kg0 * 8;
  const unsigned short* gk1 = kbase + (size_t)kr1 * HDIM + kg1 * 8;
  const unsigned short* gv0 = vbase + (size_t)kr0 * SEQ + kg0 * 8;
  const unsigned short* gv1 = vbase + (size_t)kr1 * SEQ + kg1 * 8;
  unsigned short* lk0 = Ks + (w * 2 + 0) * 512;
  unsigned short* lk1 = Ks + (w * 2 + 1) * 512;
  unsigned short* lv0 = Vs + (w * 2 + 0) * 512;
  unsigned short* lv1 = Vs + (w * 2 + 1) * 512;

  floatx16 ot0 = {}, ot1 = {};    // O^T accum: d-groups 0-31, 32-63
  floatx16 osum = {};             // per-query softmax denominator

  const short one_bf = (short)0x3F80;  // bf16 1.0
  const short8 onesA = {one_bf, one_bf, one_bf, one_bf,
                        one_bf, one_bf, one_bf, one_bf};

  // Prefetch tile 0 into buffer 0.
  gl_lds16(gk0, lk0);
  gl_lds16(gk1, lk1);
  gl_lds16(gv0, lv0);
  gl_lds16(gv1, lv1);

  for (int kt = 0; kt < SEQ; kt += 64) {
    const int buf = (kt >> 6) & 1;
    const int boff = buf * 4096;
    __syncthreads();   // drains stage(kt) (issued one compute-phase ago) and
                       // guards buf^1 reuse (last read before prev barrier)
    if (kt + 64 < SEQ) {
      const int noff = (boff ^ 4096);
      gl_lds16(gk0 + (size_t)(kt + 64) * HDIM, lk0 + noff);
      gl_lds16(gk1 + (size_t)(kt + 64) * HDIM, lk1 + noff);
      gl_lds16(gv0 + (kt + 64), lv0 + noff);
      gl_lds16(gv1 + (kt + 64), lv1 + noff);
    }

    // S^T = K·Q^T: A[m=key][k=d] from Ks (swizzled b128), B = qa regs.
    floatx16 st0 = {}, st1 = {};
#pragma unroll
    for (int ds = 0; ds < 4; ++ds) {
      const int g = ds * 2 + h2;
      short8 ka0 = *(const short8*)&Ks[boff + q31 * 64 + ((g ^ (q31 & 7)) * 8)];
      st0 = __builtin_amdgcn_mfma_f32_32x32x16_bf16(ka0, qa[ds], st0, 0, 0, 0);
      const int k1 = 32 + q31;
      short8 ka1 = *(const short8*)&Ks[boff + k1 * 64 + ((g ^ (k1 & 7)) * 8)];
      st1 = __builtin_amdgcn_mfma_f32_32x32x16_bf16(ka1, qa[ds], st1, 0, 0, 0);
    }

    // P^T = exp2(S^T), packed as bf16 pairs; cross-half copies via shfl.
    unsigned pk0[8], pk1[8], sw0[8], sw1[8];
#pragma unroll
    for (int i = 0; i < 8; ++i) {
      pk0[i] = pack2bf(EXP2(st0[2 * i]), EXP2(st0[2 * i + 1]));
      sw0[i] = __shfl_xor(pk0[i], 32);
      pk1[i] = pack2bf(EXP2(st1[2 * i]), EXP2(st1[2 * i + 1]));
      sw1[i] = __shfl_xor(pk1[i], 32);
    }

    // PV: O^T += V^T·P^T over 4 global ksteps of 16 keys.
#pragma unroll
    for (int kst = 0; kst < 4; ++kst) {
      const unsigned* pk = (kst < 2) ? pk0 : pk1;
      const unsigned* sw = (kst < 2) ? sw0 : sw1;
      const int kl = kst & 1;
      union { unsigned u[4]; short8 s; } pb;
      pb.u[0] = h2 ? sw[4 * kl + 2] : pk[4 * kl + 0];
      pb.u[1] = h2 ? sw[4 * kl + 3] : pk[4 * kl + 1];
      pb.u[2] = h2 ? pk[4 * kl + 2] : sw[4 * kl + 0];
      pb.u[3] = h2 ? pk[4 * kl + 3] : sw[4 * kl + 1];

      osum = __builtin_amdgcn_mfma_f32_32x32x16_bf16(onesA, pb.s, osum, 0, 0, 0);

      const int g = kst * 2 + h2;
      short8 va0 = *(const short8*)&Vs[boff + q31 * 64 + ((g ^ (q31 & 7)) * 8)];
      ot0 = __builtin_amdgcn_mfma_f32_32x32x16_bf16(va0, pb.s, ot0, 0, 0, 0);
      const int d1 = 32 + q31;
      short8 va1 = *(const short8*)&Vs[boff + d1 * 64 + ((g ^ (d1 & 7)) * 8)];
      ot1 = __builtin_amdgcn_mfma_f32_32x32x16_bf16(va1, pb.s, ot1, 0, 0, 0);
    }
  }

  // osum: every reg holds this lane's query row-sum (cols = queries).
  const float inv = 1.0f / osum[0];

  // O^T C-layout: col=q (lane), row=d=(reg&3)+8*(reg>>2)+4*h2 (+32 for ot1).
  const int b = bh >> 4, hh = bh & 15;
  unsigned short* orow =
      aout + ((size_t)b * SEQ + qBase + w * 32 + q31) * EMBED + hh * HDIM;
#pragma unroll
  for (int rg = 0; rg < 4; ++rg) {
    const int d0 = rg * 8 + h2 * 4;
    ushort4 p0, p1;
    p0.x = f2bf(ot0[4 * rg + 0] * inv); p0.y = f2bf(ot0[4 * rg + 1] * inv);
    p0.z = f2bf(ot0[4 * rg + 2] * inv); p0.w = f2bf(ot0[4 * rg + 3] * inv);
    *(ushort4*)(orow + d0) = p0;
    p1.x = f2bf(ot1[4 * rg + 0] * inv); p1.y = f2bf(ot1[4 * rg + 1] * inv);
    p1.z = f2bf(ot1[4 * rg + 2] * inv); p1.w = f2bf(ot1[4 * rg + 3] * inv);
    *(ushort4*)(orow + 32 + d0) = p1;
  }
}

// ---------------------------------------------------------------------------
// Output projection: fp32 result straight from accumulators.
// ---------------------------------------------------------------------------
__global__ __launch_bounds__(256) void out_proj_bf16(
    const unsigned short* __restrict__ aout,
    const unsigned short* __restrict__ wb,
    float* __restrict__ Cout) {
  const int nBase = blockIdx.x * 128;
  const int mBase = blockIdx.y * 128;

  __shared__ unsigned short As[128 * 32];
  __shared__ unsigned short Bs[128 * 32];

  floatx4 acc[4][4] = {};
  gemm_core(aout, wb + ((size_t)3 << 20), mBase, nBase, As, Bs, acc);

  const int t = threadIdx.x;
  const int lane = t & 63, w = t >> 6;
  const int wr = w >> 1, wc = w & 1;
  const int quad = lane >> 4, l15 = lane & 15;

#pragma unroll
  for (int mi = 0; mi < 4; ++mi)
#pragma unroll
    for (int ni = 0; ni < 4; ++ni) {
      const int n = nBase + wc * 64 + ni * 16 + l15;
#pragma unroll
      for (int r = 0; r < 4; ++r) {
        const int m = mBase + wr * 64 + mi * 16 + quad * 4 + r;
        Cout[(size_t)m * EMBED + n] = acc[mi][ni][r];
      }
    }
}

extern "C" void kernel_launch(void* const* d_in, const int* in_sizes, int n_in,
                              void* d_out, int out_size, void* d_ws, size_t ws_size,
                              hipStream_t stream) {
  const float* x  = (const float*)d_in[0];
  const float* wq = (const float*)d_in[1];
  const float* wk = (const float*)d_in[2];
  const float* wv = (const float*)d_in[3];
  const float* wo = (const float*)d_in[4];
  float* out = (float*)d_out;

  char* ws = (char*)d_ws;
  unsigned short* xb   = (unsigned short*)(ws);                  // 16.8 MB
  unsigned short* wb   = (unsigned short*)(ws + (16u << 20));    // 8.4 MB
  unsigned short* qkv  = (unsigned short*)(ws + (26u << 20));    // 50.3 MB
  unsigned short* aout = (unsigned short*)(ws + (76u << 20));    // 16.8 MB

  cast_bf16_kernel<<<12288, 256, 0, stream>>>(x, wq, wk, wv, wo, xb, wb);
  proj_qkv_bf16<<<dim3(EMBED / 128, MROWS / 128, 3), 256, 0, stream>>>(xb, wb, qkv);
  attn_mfma<<<1024, 256, 0, stream>>>(qkv, aout);
  out_proj_bf16<<<dim3(EMBED / 128, MROWS / 128), 256, 0, stream>>>(aout, wb, out);
}

// Round 6
// 315.968 us; speedup vs baseline: 1.0156x; 1.0156x over previous
//
#include <hip/hip_runtime.h>
#include <math.h>

#define EMBED 1024
#define NHEAD 16
#define HDIM  64
#define BATCH 4
#define SEQ   2048
#define MROWS (BATCH * SEQ)   // 8192

typedef __attribute__((ext_vector_type(8))) short short8;
typedef __attribute__((ext_vector_type(4))) float floatx4;
typedef __attribute__((ext_vector_type(16))) float floatx16;

#if __has_builtin(__builtin_amdgcn_exp2f)
#define EXP2(x) __builtin_amdgcn_exp2f(x)
#else
#define EXP2(x) exp2f(x)
#endif

// RNE float -> bf16 (finite inputs only).
__device__ __forceinline__ unsigned short f2bf(float f) {
  unsigned u = __float_as_uint(f);
  u += 0x7fffu + ((u >> 16) & 1u);
  return (unsigned short)(u >> 16);
}

// Pack two floats as a bf16 pair. gfx950 has v_cvt_pk_bf16_f32 (1 VALU op).
#if __has_builtin(__builtin_amdgcn_cvt_pk_bf16_f32)
__device__ __forceinline__ unsigned pack2bf(float lo, float hi) {
  typedef __attribute__((ext_vector_type(2))) __bf16 bf2;
  union { bf2 b; unsigned u; } c;
  c.b = __builtin_amdgcn_cvt_pk_bf16_f32(lo, hi);
  return c.u;
}
#else
__device__ __forceinline__ unsigned pack2bf(float lo, float hi) {
  return ((__float_as_uint(lo) + 0x8000u) >> 16) |
         ((__float_as_uint(hi) + 0x8000u) & 0xffff0000u);
}
#endif

// Async global->LDS, 16 B per lane. lds dest = uniform base + lane*16.
__device__ __forceinline__ void gl_lds16(const void* g, void* l) {
  __builtin_amdgcn_global_load_lds(
      (const __attribute__((address_space(1))) unsigned int*)g,
      (__attribute__((address_space(3))) unsigned int*)l, 16, 0, 0);
}

// ---------------------------------------------------------------------------
// Cast fp32 -> bf16: x (8M elems) + 4 weights (1M each, contiguous dst).
// ---------------------------------------------------------------------------
__global__ __launch_bounds__(256) void cast_bf16_kernel(
    const float* __restrict__ x,  const float* __restrict__ wq,
    const float* __restrict__ wk, const float* __restrict__ wv,
    const float* __restrict__ wo,
    unsigned short* __restrict__ xb, unsigned short* __restrict__ wb) {
  const size_t NX = (size_t)MROWS * EMBED;                 // 2^23
  size_t i4 = ((size_t)blockIdx.x * 256 + threadIdx.x) * 4;
  const float* src;
  unsigned short* dst;
  size_t off;
  if (i4 < NX) {
    src = x; dst = xb; off = i4;
  } else {
    size_t j = i4 - NX;
    int r = (int)(j >> 20);
    off = j & ((1u << 20) - 1);
    src = (r == 0) ? wq : (r == 1) ? wk : (r == 2) ? wv : wo;
    dst = wb + ((size_t)r << 20);
  }
  float4 v = *(const float4*)(src + off);
  ushort4 o;
  o.x = f2bf(v.x); o.y = f2bf(v.y); o.z = f2bf(v.z); o.w = f2bf(v.w);
  *(ushort4*)(dst + off) = o;
}

// ---------------------------------------------------------------------------
// Shared 128x128xK bf16 GEMM core (m97 structure): Y = A @ B^T fragments.
// ---------------------------------------------------------------------------
__device__ __forceinline__ void gemm_core(
    const unsigned short* __restrict__ Amat,
    const unsigned short* __restrict__ Bmat,
    int mBase, int nBase,
    unsigned short* As, unsigned short* Bs,
    floatx4 acc[4][4]) {
  const int t = threadIdx.x;
  const int lane = t & 63, w = t >> 6;
  const int wr = w >> 1, wc = w & 1;
  const int quad = lane >> 4, l15 = lane & 15;

  const int f0 = (w * 2 + 0) * 64 + lane;
  const int f1 = (w * 2 + 1) * 64 + lane;
  const unsigned short* ga0 = Amat + (size_t)(mBase + (f0 >> 2)) * EMBED + (f0 & 3) * 8;
  const unsigned short* ga1 = Amat + (size_t)(mBase + (f1 >> 2)) * EMBED + (f1 & 3) * 8;
  const unsigned short* gb0 = Bmat + (size_t)(nBase + (f0 >> 2)) * EMBED + (f0 & 3) * 8;
  const unsigned short* gb1 = Bmat + (size_t)(nBase + (f1 >> 2)) * EMBED + (f1 & 3) * 8;
  unsigned short* la0 = As + (w * 2 + 0) * 512;
  unsigned short* la1 = As + (w * 2 + 1) * 512;
  unsigned short* lb0 = Bs + (w * 2 + 0) * 512;
  unsigned short* lb1 = Bs + (w * 2 + 1) * 512;

  for (int kb = 0; kb < EMBED; kb += 32) {
    __syncthreads();
    gl_lds16(ga0 + kb, la0);
    gl_lds16(ga1 + kb, la1);
    gl_lds16(gb0 + kb, lb0);
    gl_lds16(gb1 + kb, lb1);
    __syncthreads();
    short8 a[4], b[4];
#pragma unroll
    for (int mi = 0; mi < 4; ++mi)
      a[mi] = *(const short8*)&As[(wr * 64 + mi * 16 + l15) * 32 + quad * 8];
#pragma unroll
    for (int ni = 0; ni < 4; ++ni)
      b[ni] = *(const short8*)&Bs[(wc * 64 + ni * 16 + l15) * 32 + quad * 8];
#pragma unroll
    for (int mi = 0; mi < 4; ++mi)
#pragma unroll
      for (int ni = 0; ni < 4; ++ni)
        acc[mi][ni] = __builtin_amdgcn_mfma_f32_16x16x32_bf16(
            a[mi], b[ni], acc[mi][ni], 0, 0, 0);
  }
}

// ---------------------------------------------------------------------------
// QKV projection. Q is pre-scaled by C=(1/8)*log2(e) so attention's exp2
// argument is the raw QK^T score. Q,K: bf16 [b,h,s,d]; V: [b,h,d,s].
// ---------------------------------------------------------------------------
__global__ __launch_bounds__(256) void proj_qkv_bf16(
    const unsigned short* __restrict__ xb,
    const unsigned short* __restrict__ wb,
    unsigned short* __restrict__ qkv) {
  const int which = blockIdx.z;
  const unsigned short* W = wb + ((size_t)which << 20);
  const int nBase = blockIdx.x * 128;
  const int mBase = blockIdx.y * 128;

  __shared__ unsigned short As[128 * 32];
  __shared__ unsigned short Bs[128 * 32];

  floatx4 acc[4][4] = {};
  gemm_core(xb, W, mBase, nBase, As, Bs, acc);

  const int t = threadIdx.x;
  const int lane = t & 63, w = t >> 6;
  const int wr = w >> 1, wc = w & 1;
  const int quad = lane >> 4, l15 = lane & 15;

  unsigned short* out = qkv + (size_t)which * MROWS * EMBED;
  if (which < 2) {
    const float scale = (which == 0) ? 0.18033688f : 1.0f;  // (1/8)*log2(e)
#pragma unroll
    for (int mi = 0; mi < 4; ++mi)
#pragma unroll
      for (int ni = 0; ni < 4; ++ni) {
        const int n = nBase + wc * 64 + ni * 16 + l15;
        const int h = n >> 6, d = n & 63;
#pragma unroll
        for (int r = 0; r < 4; ++r) {
          const int m = mBase + wr * 64 + mi * 16 + quad * 4 + r;
          const int b = m >> 11, s = m & (SEQ - 1);
          out[(((size_t)(b * NHEAD + h) * SEQ) + s) * HDIM + d] =
              f2bf(acc[mi][ni][r] * scale);
        }
      }
  } else {
    // V^T: [b,h,d,s] — 4 consecutive s per lane -> packed 8 B store.
#pragma unroll
    for (int mi = 0; mi < 4; ++mi) {
      const int m0 = mBase + wr * 64 + mi * 16 + quad * 4;
      const int b = m0 >> 11, s0 = m0 & (SEQ - 1);
#pragma unroll
      for (int ni = 0; ni < 4; ++ni) {
        const int n = nBase + wc * 64 + ni * 16 + l15;
        const int h = n >> 6, d = n & 63;
        ushort4 pk;
        pk.x = f2bf(acc[mi][ni][0]); pk.y = f2bf(acc[mi][ni][1]);
        pk.z = f2bf(acc[mi][ni][2]); pk.w = f2bf(acc[mi][ni][3]);
        *(ushort4*)&out[((size_t)(b * NHEAD + h) * HDIM + d) * SEQ + s0] = pk;
      }
    }
  }
}

// ---------------------------------------------------------------------------
// MFMA flash attention, 32x32x16, transposed-score.
// R6: single-buffer two-barrier staging (R4 structure — no LDS-alias vmcnt
// stalls), XCD-swizzled grid (K/V from per-XCD L2; FETCH 139->25 MB), and
// 128-key staged tiles (16 barrier pairs instead of 32; staging VALU
// amortized over 2x compute).
// ---------------------------------------------------------------------------
__global__ __launch_bounds__(256) void attn_mfma(
    const unsigned short* __restrict__ qkv,
    unsigned short* __restrict__ aout) {
  const unsigned short* Q = qkv;
  const unsigned short* K = qkv + (size_t)MROWS * EMBED;
  const unsigned short* V = qkv + 2 * (size_t)MROWS * EMBED;

  // XCD-locality decode: all 16 q-blocks of one bh land on one XCD.
  const int id = blockIdx.x;
  const int xcd = id & 7, slot = id >> 3;
  const int bh = xcd * 8 + (slot >> 4);
  const int qBase = (slot & 15) * 128;

  __shared__ unsigned short Ks[128 * 64];   // [key][d], XOR-8 swizzled
  __shared__ unsigned short Vs[64 * 128];   // [d][key], XOR-16 swizzled

  const int t = threadIdx.x;
  const int lane = t & 63, w = t >> 6;
  const int h2 = lane >> 5;     // lane half (k-group selector in A/B frags)
  const int q31 = lane & 31;    // query within wave / col within tile

  // Q B-frags (pre-scaled by (1/8)*log2e): B[k=d][n=q].
  const unsigned short* qrow =
      Q + ((size_t)bh * SEQ + qBase + w * 32 + q31) * HDIM;
  short8 qa[4];
#pragma unroll
  for (int ds = 0; ds < 4; ++ds)
    qa[ds] = *(const short8*)(qrow + ds * 16 + h2 * 8);

  // Staging addresses (hoisted, loop adds only kt term).
  // K: 8192 elems = 1024 16B-chunks; chunk c -> row=c>>3, grp=(c&7)^(row&7).
  // V: chunk c -> d=c>>4, pos=c&15 holds source chunk j=pos^(d&15).
  const unsigned short* kbase = K + (size_t)bh * SEQ * HDIM;
  const unsigned short* vbase = V + (size_t)bh * HDIM * SEQ;
  const unsigned short* gk[4];
  const unsigned short* gv[4];
  unsigned short* lk[4];
  unsigned short* lv[4];
#pragma unroll
  for (int i = 0; i < 4; ++i) {
    const int c = (w * 4 + i) * 64 + lane;
    const int krow = c >> 3, kgrp = (c & 7) ^ (krow & 7);
    gk[i] = kbase + (size_t)krow * HDIM + kgrp * 8;
    const int vd = c >> 4, vj = (c & 15) ^ (vd & 15);
    gv[i] = vbase + (size_t)vd * SEQ + vj * 8;
    lk[i] = Ks + (w * 4 + i) * 512;
    lv[i] = Vs + (w * 4 + i) * 512;
  }

  floatx16 ot0 = {}, ot1 = {};    // O^T accum: d-groups 0-31, 32-63
  floatx16 osum = {};             // per-query softmax denominator

  const short one_bf = (short)0x3F80;  // bf16 1.0
  const short8 onesA = {one_bf, one_bf, one_bf, one_bf,
                        one_bf, one_bf, one_bf, one_bf};

  for (int kt = 0; kt < SEQ; kt += 128) {
    __syncthreads();   // all waves done reading previous tile
#pragma unroll
    for (int i = 0; i < 4; ++i) {
      gl_lds16(gk[i] + (size_t)kt * HDIM, lk[i]);
      gl_lds16(gv[i] + kt, lv[i]);
    }
    __syncthreads();   // staging visible (vmcnt drain here only)

#pragma unroll
    for (int sub = 0; sub < 2; ++sub) {
      const int koff = sub * 64;

      // S^T = K·Q^T: A[m=key][k=d] from Ks (swizzled b128), B = qa regs.
      floatx16 st0 = {}, st1 = {};
#pragma unroll
      for (int ds = 0; ds < 4; ++ds) {
        const int g = ds * 2 + h2;
        const int k0 = koff + q31;
        short8 ka0 = *(const short8*)&Ks[k0 * 64 + ((g ^ (q31 & 7)) * 8)];
        st0 = __builtin_amdgcn_mfma_f32_32x32x16_bf16(ka0, qa[ds], st0, 0, 0, 0);
        const int k1 = koff + 32 + q31;
        short8 ka1 = *(const short8*)&Ks[k1 * 64 + ((g ^ (q31 & 7)) * 8)];
        st1 = __builtin_amdgcn_mfma_f32_32x32x16_bf16(ka1, qa[ds], st1, 0, 0, 0);
      }

      // P^T = exp2(S^T), packed bf16 pairs; cross-half copies via shfl.
      unsigned pk0[8], pk1[8], sw0[8], sw1[8];
#pragma unroll
      for (int i = 0; i < 8; ++i) {
        pk0[i] = pack2bf(EXP2(st0[2 * i]), EXP2(st0[2 * i + 1]));
        sw0[i] = __shfl_xor(pk0[i], 32);
        pk1[i] = pack2bf(EXP2(st1[2 * i]), EXP2(st1[2 * i + 1]));
        sw1[i] = __shfl_xor(pk1[i], 32);
      }

      // PV: O^T += V^T·P^T over 4 ksteps of 16 keys.
#pragma unroll
      for (int kst = 0; kst < 4; ++kst) {
        const unsigned* pk = (kst < 2) ? pk0 : pk1;
        const unsigned* sw = (kst < 2) ? sw0 : sw1;
        const int kl = kst & 1;
        union { unsigned u[4]; short8 s; } pb;
        pb.u[0] = h2 ? sw[4 * kl + 2] : pk[4 * kl + 0];
        pb.u[1] = h2 ? sw[4 * kl + 3] : pk[4 * kl + 1];
        pb.u[2] = h2 ? pk[4 * kl + 2] : sw[4 * kl + 0];
        pb.u[3] = h2 ? pk[4 * kl + 3] : sw[4 * kl + 1];

        osum = __builtin_amdgcn_mfma_f32_32x32x16_bf16(onesA, pb.s, osum, 0, 0, 0);

        const int j = sub * 8 + kst * 2 + h2;
        short8 va0 = *(const short8*)&Vs[q31 * 128 + ((j ^ (q31 & 15)) * 8)];
        ot0 = __builtin_amdgcn_mfma_f32_32x32x16_bf16(va0, pb.s, ot0, 0, 0, 0);
        const int d1 = 32 + q31;
        short8 va1 = *(const short8*)&Vs[d1 * 128 + ((j ^ (d1 & 15)) * 8)];
        ot1 = __builtin_amdgcn_mfma_f32_32x32x16_bf16(va1, pb.s, ot1, 0, 0, 0);
      }
    }
  }

  // osum: every reg holds this lane's query row-sum (cols = queries).
  const float inv = 1.0f / osum[0];

  // O^T C-layout: col=q (lane), row=d=(reg&3)+8*(reg>>2)+4*h2 (+32 for ot1).
  const int b = bh >> 4, hh = bh & 15;
  unsigned short* orow =
      aout + ((size_t)b * SEQ + qBase + w * 32 + q31) * EMBED + hh * HDIM;
#pragma unroll
  for (int rg = 0; rg < 4; ++rg) {
    const int d0 = rg * 8 + h2 * 4;
    ushort4 p0, p1;
    p0.x = f2bf(ot0[4 * rg + 0] * inv); p0.y = f2bf(ot0[4 * rg + 1] * inv);
    p0.z = f2bf(ot0[4 * rg + 2] * inv); p0.w = f2bf(ot0[4 * rg + 3] * inv);
    *(ushort4*)(orow + d0) = p0;
    p1.x = f2bf(ot1[4 * rg + 0] * inv); p1.y = f2bf(ot1[4 * rg + 1] * inv);
    p1.z = f2bf(ot1[4 * rg + 2] * inv); p1.w = f2bf(ot1[4 * rg + 3] * inv);
    *(ushort4*)(orow + 32 + d0) = p1;
  }
}

// ---------------------------------------------------------------------------
// Output projection: fp32 result straight from accumulators.
// ---------------------------------------------------------------------------
__global__ __launch_bounds__(256) void out_proj_bf16(
    const unsigned short* __restrict__ aout,
    const unsigned short* __restrict__ wb,
    float* __restrict__ Cout) {
  const int nBase = blockIdx.x * 128;
  const int mBase = blockIdx.y * 128;

  __shared__ unsigned short As[128 * 32];
  __shared__ unsigned short Bs[128 * 32];

  floatx4 acc[4][4] = {};
  gemm_core(aout, wb + ((size_t)3 << 20), mBase, nBase, As, Bs, acc);

  const int t = threadIdx.x;
  const int lane = t & 63, w = t >> 6;
  const int wr = w >> 1, wc = w & 1;
  const int quad = lane >> 4, l15 = lane & 15;

#pragma unroll
  for (int mi = 0; mi < 4; ++mi)
#pragma unroll
    for (int ni = 0; ni < 4; ++ni) {
      const int n = nBase + wc * 64 + ni * 16 + l15;
#pragma unroll
      for (int r = 0; r < 4; ++r) {
        const int m = mBase + wr * 64 + mi * 16 + quad * 4 + r;
        Cout[(size_t)m * EMBED + n] = acc[mi][ni][r];
      }
    }
}

extern "C" void kernel_launch(void* const* d_in, const int* in_sizes, int n_in,
                              void* d_out, int out_size, void* d_ws, size_t ws_size,
                              hipStream_t stream) {
  const float* x  = (const float*)d_in[0];
  const float* wq = (const float*)d_in[1];
  const float* wk = (const float*)d_in[2];
  const float* wv = (const float*)d_in[3];
  const float* wo = (const float*)d_in[4];
  float* out = (float*)d_out;

  char* ws = (char*)d_ws;
  unsigned short* xb   = (unsigned short*)(ws);                  // 16.8 MB
  unsigned short* wb   = (unsigned short*)(ws + (16u << 20));    // 8.4 MB
  unsigned short* qkv  = (unsigned short*)(ws + (26u << 20));    // 50.3 MB
  unsigned short* aout = (unsigned short*)(ws + (76u << 20));    // 16.8 MB

  cast_bf16_kernel<<<12288, 256, 0, stream>>>(x, wq, wk, wv, wo, xb, wb);
  proj_qkv_bf16<<<dim3(EMBED / 128, MROWS / 128, 3), 256, 0, stream>>>(xb, wb, qkv);
  attn_mfma<<<1024, 256, 0, stream>>>(qkv, aout);
  out_proj_bf16<<<dim3(EMBED / 128, MROWS / 128), 256, 0, stream>>>(aout, wb, out);
}

// Round 7
// 301.148 us; speedup vs baseline: 1.0656x; 1.0492x over previous
//
#include <hip/hip_runtime.h>
#include <math.h>

#define EMBED 1024
#define NHEAD 16
#define HDIM  64
#define BATCH 4
#define SEQ   2048
#define MROWS (BATCH * SEQ)   // 8192

typedef __attribute__((ext_vector_type(4))) short short4v;
typedef __attribute__((ext_vector_type(8))) short short8;
typedef __attribute__((ext_vector_type(4))) float floatx4;
typedef __attribute__((ext_vector_type(16))) float floatx16;

#if __has_builtin(__builtin_amdgcn_exp2f)
#define EXP2(x) __builtin_amdgcn_exp2f(x)
#else
#define EXP2(x) exp2f(x)
#endif

// RNE float -> bf16 (finite inputs only).
__device__ __forceinline__ unsigned short f2bf(float f) {
  unsigned u = __float_as_uint(f);
  u += 0x7fffu + ((u >> 16) & 1u);
  return (unsigned short)(u >> 16);
}

// Pack two floats as a bf16 pair. gfx950 has v_cvt_pk_bf16_f32 (1 VALU op).
#if __has_builtin(__builtin_amdgcn_cvt_pk_bf16_f32)
__device__ __forceinline__ unsigned pack2bf(float lo, float hi) {
  typedef __attribute__((ext_vector_type(2))) __bf16 bf2;
  union { bf2 b; unsigned u; } c;
  c.b = __builtin_amdgcn_cvt_pk_bf16_f32(lo, hi);
  return c.u;
}
#else
__device__ __forceinline__ unsigned pack2bf(float lo, float hi) {
  return ((__float_as_uint(lo) + 0x8000u) >> 16) |
         ((__float_as_uint(hi) + 0x8000u) & 0xffff0000u);
}
#endif

// Async global->LDS, 16 B per lane. lds dest = uniform base + lane*16.
__device__ __forceinline__ void gl_lds16(const void* g, void* l) {
  __builtin_amdgcn_global_load_lds(
      (const __attribute__((address_space(1))) unsigned int*)g,
      (__attribute__((address_space(3))) unsigned int*)l, 16, 0, 0);
}

// ---------------------------------------------------------------------------
// Cast fp32 -> bf16: x (8M elems) + 4 weights (1M each, contiguous dst).
// ---------------------------------------------------------------------------
__global__ __launch_bounds__(256) void cast_bf16_kernel(
    const float* __restrict__ x,  const float* __restrict__ wq,
    const float* __restrict__ wk, const float* __restrict__ wv,
    const float* __restrict__ wo,
    unsigned short* __restrict__ xb, unsigned short* __restrict__ wb) {
  const size_t NX = (size_t)MROWS * EMBED;                 // 2^23
  size_t i4 = ((size_t)blockIdx.x * 256 + threadIdx.x) * 4;
  const float* src;
  unsigned short* dst;
  size_t off;
  if (i4 < NX) {
    src = x; dst = xb; off = i4;
  } else {
    size_t j = i4 - NX;
    int r = (int)(j >> 20);
    off = j & ((1u << 20) - 1);
    src = (r == 0) ? wq : (r == 1) ? wk : (r == 2) ? wv : wo;
    dst = wb + ((size_t)r << 20);
  }
  float4 v = *(const float4*)(src + off);
  ushort4 o;
  o.x = f2bf(v.x); o.y = f2bf(v.y); o.z = f2bf(v.z); o.w = f2bf(v.w);
  *(ushort4*)(dst + off) = o;
}

// ---------------------------------------------------------------------------
// Shared 128x128xK bf16 GEMM core (m97 structure): Y = A @ B^T fragments.
// ---------------------------------------------------------------------------
__device__ __forceinline__ void gemm_core(
    const unsigned short* __restrict__ Amat,
    const unsigned short* __restrict__ Bmat,
    int mBase, int nBase,
    unsigned short* As, unsigned short* Bs,
    floatx4 acc[4][4]) {
  const int t = threadIdx.x;
  const int lane = t & 63, w = t >> 6;
  const int wr = w >> 1, wc = w & 1;
  const int quad = lane >> 4, l15 = lane & 15;

  const int f0 = (w * 2 + 0) * 64 + lane;
  const int f1 = (w * 2 + 1) * 64 + lane;
  const unsigned short* ga0 = Amat + (size_t)(mBase + (f0 >> 2)) * EMBED + (f0 & 3) * 8;
  const unsigned short* ga1 = Amat + (size_t)(mBase + (f1 >> 2)) * EMBED + (f1 & 3) * 8;
  const unsigned short* gb0 = Bmat + (size_t)(nBase + (f0 >> 2)) * EMBED + (f0 & 3) * 8;
  const unsigned short* gb1 = Bmat + (size_t)(nBase + (f1 >> 2)) * EMBED + (f1 & 3) * 8;
  unsigned short* la0 = As + (w * 2 + 0) * 512;
  unsigned short* la1 = As + (w * 2 + 1) * 512;
  unsigned short* lb0 = Bs + (w * 2 + 0) * 512;
  unsigned short* lb1 = Bs + (w * 2 + 1) * 512;

  for (int kb = 0; kb < EMBED; kb += 32) {
    __syncthreads();
    gl_lds16(ga0 + kb, la0);
    gl_lds16(ga1 + kb, la1);
    gl_lds16(gb0 + kb, lb0);
    gl_lds16(gb1 + kb, lb1);
    __syncthreads();
    short8 a[4], b[4];
#pragma unroll
    for (int mi = 0; mi < 4; ++mi)
      a[mi] = *(const short8*)&As[(wr * 64 + mi * 16 + l15) * 32 + quad * 8];
#pragma unroll
    for (int ni = 0; ni < 4; ++ni)
      b[ni] = *(const short8*)&Bs[(wc * 64 + ni * 16 + l15) * 32 + quad * 8];
#pragma unroll
    for (int mi = 0; mi < 4; ++mi)
#pragma unroll
      for (int ni = 0; ni < 4; ++ni)
        acc[mi][ni] = __builtin_amdgcn_mfma_f32_16x16x32_bf16(
            a[mi], b[ni], acc[mi][ni], 0, 0, 0);
  }
}

// ---------------------------------------------------------------------------
// QKV projection. Q is pre-scaled by C=(1/8)*log2(e) so attention's exp2
// argument is the raw QK^T score. Q,K: bf16 [b,h,s,d]; V: [b,h,d,s].
// ---------------------------------------------------------------------------
__global__ __launch_bounds__(256) void proj_qkv_bf16(
    const unsigned short* __restrict__ xb,
    const unsigned short* __restrict__ wb,
    unsigned short* __restrict__ qkv) {
  const int which = blockIdx.z;
  const unsigned short* W = wb + ((size_t)which << 20);
  const int nBase = blockIdx.x * 128;
  const int mBase = blockIdx.y * 128;

  __shared__ unsigned short As[128 * 32];
  __shared__ unsigned short Bs[128 * 32];

  floatx4 acc[4][4] = {};
  gemm_core(xb, W, mBase, nBase, As, Bs, acc);

  const int t = threadIdx.x;
  const int lane = t & 63, w = t >> 6;
  const int wr = w >> 1, wc = w & 1;
  const int quad = lane >> 4, l15 = lane & 15;

  unsigned short* out = qkv + (size_t)which * MROWS * EMBED;
  if (which < 2) {
    const float scale = (which == 0) ? 0.18033688f : 1.0f;  // (1/8)*log2(e)
#pragma unroll
    for (int mi = 0; mi < 4; ++mi)
#pragma unroll
      for (int ni = 0; ni < 4; ++ni) {
        const int n = nBase + wc * 64 + ni * 16 + l15;
        const int h = n >> 6, d = n & 63;
#pragma unroll
        for (int r = 0; r < 4; ++r) {
          const int m = mBase + wr * 64 + mi * 16 + quad * 4 + r;
          const int b = m >> 11, s = m & (SEQ - 1);
          out[(((size_t)(b * NHEAD + h) * SEQ) + s) * HDIM + d] =
              f2bf(acc[mi][ni][r] * scale);
        }
      }
  } else {
    // V^T: [b,h,d,s] — 4 consecutive s per lane -> packed 8 B store.
#pragma unroll
    for (int mi = 0; mi < 4; ++mi) {
      const int m0 = mBase + wr * 64 + mi * 16 + quad * 4;
      const int b = m0 >> 11, s0 = m0 & (SEQ - 1);
#pragma unroll
      for (int ni = 0; ni < 4; ++ni) {
        const int n = nBase + wc * 64 + ni * 16 + l15;
        const int h = n >> 6, d = n & 63;
        ushort4 pk;
        pk.x = f2bf(acc[mi][ni][0]); pk.y = f2bf(acc[mi][ni][1]);
        pk.z = f2bf(acc[mi][ni][2]); pk.w = f2bf(acc[mi][ni][3]);
        *(ushort4*)&out[((size_t)(b * NHEAD + h) * HDIM + d) * SEQ + s0] = pk;
      }
    }
  }
}

// ---------------------------------------------------------------------------
// MFMA flash attention, transposed-score formulation.
// R7: PV uses v_mfma_f32_32x32x8_bf16 (K=8). Its B-operand k-slots
// (k=h2*4+j) coincide exactly with the S^T C-layout rows owned by each
// lane (rows (r&3)+8*(r>>2)+4*h2), so the packed exp2 pairs ARE the PV
// B-fragments: no cross-lane bpermute, no selects. Softmax denominator:
// every S^T reg belongs to the lane's own query -> per-lane fp32 sum +
// one shfl_xor(32) at the end (frees the 16-reg ones-MFMA accumulator).
// ---------------------------------------------------------------------------
__global__ __launch_bounds__(256) void attn_mfma(
    const unsigned short* __restrict__ qkv,
    unsigned short* __restrict__ aout) {
  const unsigned short* Q = qkv;
  const unsigned short* K = qkv + (size_t)MROWS * EMBED;
  const unsigned short* V = qkv + 2 * (size_t)MROWS * EMBED;

  // XCD-locality decode: all 16 q-blocks of one bh land on one XCD.
  const int id = blockIdx.x;
  const int xcd = id & 7, slot = id >> 3;
  const int bh = xcd * 8 + (slot >> 4);
  const int qBase = (slot & 15) * 128;

  __shared__ unsigned short Ks[128 * 64];   // [key][d], XOR-8 swizzled
  __shared__ unsigned short Vs[64 * 128];   // [d][key], XOR-16 swizzled

  const int t = threadIdx.x;
  const int lane = t & 63, w = t >> 6;
  const int h2 = lane >> 5;     // lane half (k-group selector in A/B frags)
  const int q31 = lane & 31;    // query within wave / col within tile

  // Q B-frags (pre-scaled by (1/8)*log2e): B[k=d][n=q].
  const unsigned short* qrow =
      Q + ((size_t)bh * SEQ + qBase + w * 32 + q31) * HDIM;
  short8 qa[4];
#pragma unroll
  for (int ds = 0; ds < 4; ++ds)
    qa[ds] = *(const short8*)(qrow + ds * 16 + h2 * 8);

  // Staging addresses (hoisted, loop adds only kt term).
  const unsigned short* kbase = K + (size_t)bh * SEQ * HDIM;
  const unsigned short* vbase = V + (size_t)bh * HDIM * SEQ;
  const unsigned short* gk[4];
  const unsigned short* gv[4];
  unsigned short* lk[4];
  unsigned short* lv[4];
#pragma unroll
  for (int i = 0; i < 4; ++i) {
    const int c = (w * 4 + i) * 64 + lane;
    const int krow = c >> 3, kgrp = (c & 7) ^ (krow & 7);
    gk[i] = kbase + (size_t)krow * HDIM + kgrp * 8;
    const int vd = c >> 4, vj = (c & 15) ^ (vd & 15);
    gv[i] = vbase + (size_t)vd * SEQ + vj * 8;
    lk[i] = Ks + (w * 4 + i) * 512;
    lv[i] = Vs + (w * 4 + i) * 512;
  }

  floatx16 ot0 = {}, ot1 = {};    // O^T accum: d-groups 0-31, 32-63
  float lacc = 0.0f;              // per-lane partial softmax denominator

  for (int kt = 0; kt < SEQ; kt += 128) {
    __syncthreads();   // all waves done reading previous tile
#pragma unroll
    for (int i = 0; i < 4; ++i) {
      gl_lds16(gk[i] + (size_t)kt * HDIM, lk[i]);
      gl_lds16(gv[i] + kt, lv[i]);
    }
    __syncthreads();   // staging visible (vmcnt drain here only)

#pragma unroll
    for (int sub = 0; sub < 2; ++sub) {
      const int koff = sub * 64;

      // S^T = K·Q^T: A[m=key][k=d] from Ks (swizzled b128), B = qa regs.
      floatx16 st0 = {}, st1 = {};
#pragma unroll
      for (int ds = 0; ds < 4; ++ds) {
        const int g = ds * 2 + h2;
        const int k0 = koff + q31;
        short8 ka0 = *(const short8*)&Ks[k0 * 64 + ((g ^ (q31 & 7)) * 8)];
        st0 = __builtin_amdgcn_mfma_f32_32x32x16_bf16(ka0, qa[ds], st0, 0, 0, 0);
        const int k1 = koff + 32 + q31;
        short8 ka1 = *(const short8*)&Ks[k1 * 64 + ((g ^ (q31 & 7)) * 8)];
        st1 = __builtin_amdgcn_mfma_f32_32x32x16_bf16(ka1, qa[ds], st1, 0, 0, 0);
      }

      // P^T = exp2(S^T). All of a lane's regs belong to its own query
      // (col=q31), so the denominator is a plain per-lane fp32 sum.
      float e0[16], e1[16];
#pragma unroll
      for (int i = 0; i < 16; ++i) {
        e0[i] = EXP2(st0[i]);
        e1[i] = EXP2(st1[i]);
        lacc += e0[i] + e1[i];
      }
      unsigned pk0[8], pk1[8];
#pragma unroll
      for (int i = 0; i < 8; ++i) {
        pk0[i] = pack2bf(e0[2 * i], e0[2 * i + 1]);
        pk1[i] = pack2bf(e1[2 * i], e1[2 * i + 1]);
      }

      // PV: O^T += V^T·P^T, 8 k-steps of 8 keys (32x32x8 MFMA).
      // B-frag for step s = packed regs {2*rg, 2*rg+1} (rg = s&3) — the
      // lane's own C-rows rg*8+h2*4..+3 are exactly its B k-slots.
#pragma unroll
      for (int s = 0; s < 8; ++s) {
        const unsigned* pk = (s < 4) ? pk0 : pk1;
        const int rg = s & 3;
        union { unsigned u[2]; short4v v; } pb;
        pb.u[0] = pk[2 * rg + 0];
        pb.u[1] = pk[2 * rg + 1];

        const int g = sub * 8 + s;
        const int pos = ((g ^ (q31 & 15)) * 8) + h2 * 4;
        short4v va0 = *(const short4v*)&Vs[q31 * 128 + pos];
        ot0 = __builtin_amdgcn_mfma_f32_32x32x8bf16_1k(va0, pb.v, ot0, 0, 0, 0);
        short4v va1 = *(const short4v*)&Vs[(32 + q31) * 128 + pos];
        ot1 = __builtin_amdgcn_mfma_f32_32x32x8bf16_1k(va1, pb.v, ot1, 0, 0, 0);
      }
    }
  }

  // Combine the two lane-halves' partial sums for this query.
  const float tot = lacc + __shfl_xor(lacc, 32);
  const float inv = 1.0f / tot;

  // O^T C-layout: col=q (lane), row=d=(reg&3)+8*(reg>>2)+4*h2 (+32 for ot1).
  const int b = bh >> 4, hh = bh & 15;
  unsigned short* orow =
      aout + ((size_t)b * SEQ + qBase + w * 32 + q31) * EMBED + hh * HDIM;
#pragma unroll
  for (int rg = 0; rg < 4; ++rg) {
    const int d0 = rg * 8 + h2 * 4;
    ushort4 p0, p1;
    p0.x = f2bf(ot0[4 * rg + 0] * inv); p0.y = f2bf(ot0[4 * rg + 1] * inv);
    p0.z = f2bf(ot0[4 * rg + 2] * inv); p0.w = f2bf(ot0[4 * rg + 3] * inv);
    *(ushort4*)(orow + d0) = p0;
    p1.x = f2bf(ot1[4 * rg + 0] * inv); p1.y = f2bf(ot1[4 * rg + 1] * inv);
    p1.z = f2bf(ot1[4 * rg + 2] * inv); p1.w = f2bf(ot1[4 * rg + 3] * inv);
    *(ushort4*)(orow + 32 + d0) = p1;
  }
}

// ---------------------------------------------------------------------------
// Output projection: fp32 result straight from accumulators.
// ---------------------------------------------------------------------------
__global__ __launch_bounds__(256) void out_proj_bf16(
    const unsigned short* __restrict__ aout,
    const unsigned short* __restrict__ wb,
    float* __restrict__ Cout) {
  const int nBase = blockIdx.x * 128;
  const int mBase = blockIdx.y * 128;

  __shared__ unsigned short As[128 * 32];
  __shared__ unsigned short Bs[128 * 32];

  floatx4 acc[4][4] = {};
  gemm_core(aout, wb + ((size_t)3 << 20), mBase, nBase, As, Bs, acc);

  const int t = threadIdx.x;
  const int lane = t & 63, w = t >> 6;
  const int wr = w >> 1, wc = w & 1;
  const int quad = lane >> 4, l15 = lane & 15;

#pragma unroll
  for (int mi = 0; mi < 4; ++mi)
#pragma unroll
    for (int ni = 0; ni < 4; ++ni) {
      const int n = nBase + wc * 64 + ni * 16 + l15;
#pragma unroll
      for (int r = 0; r < 4; ++r) {
        const int m = mBase + wr * 64 + mi * 16 + quad * 4 + r;
        Cout[(size_t)m * EMBED + n] = acc[mi][ni][r];
      }
    }
}

extern "C" void kernel_launch(void* const* d_in, const int* in_sizes, int n_in,
                              void* d_out, int out_size, void* d_ws, size_t ws_size,
                              hipStream_t stream) {
  const float* x  = (const float*)d_in[0];
  const float* wq = (const float*)d_in[1];
  const float* wk = (const float*)d_in[2];
  const float* wv = (const float*)d_in[3];
  const float* wo = (const float*)d_in[4];
  float* out = (float*)d_out;

  char* ws = (char*)d_ws;
  unsigned short* xb   = (unsigned short*)(ws);                  // 16.8 MB
  unsigned short* wb   = (unsigned short*)(ws + (16u << 20));    // 8.4 MB
  unsigned short* qkv  = (unsigned short*)(ws + (26u << 20));    // 50.3 MB
  unsigned short* aout = (unsigned short*)(ws + (76u << 20));    // 16.8 MB

  cast_bf16_kernel<<<12288, 256, 0, stream>>>(x, wq, wk, wv, wo, xb, wb);
  proj_qkv_bf16<<<dim3(EMBED / 128, MROWS / 128, 3), 256, 0, stream>>>(xb, wb, qkv);
  attn_mfma<<<1024, 256, 0, stream>>>(qkv, aout);
  out_proj_bf16<<<dim3(EMBED / 128, MROWS / 128), 256, 0, stream>>>(aout, wb, out);
}